// Round 2
// baseline (587.313 us; speedup 1.0000x reference)
//
#include <hip/hip_runtime.h>
#include <hip/hip_bf16.h>
#include <stdint.h>

// AdditiveAttention: B=32, S=4096, H=512, A=256
// d_out = [context: 32*512][attn: 32*4096]  (fp32)
//
// Structure (R2): single pass over enc (256 MiB).
//   prep:     bias[b][a] = dh@W_dec + b_dec + b_enc;  WT = bf16(W_enc^T)
//   fused:    per 64-row chunk: MFMA scores (A: global->VGPR->bf16->LDS stash,
//             B frags direct from L2; NO barriers in k-loop) -> tanh.We epilogue
//             -> chunk softmax (m_c,l_c) -> context partial from LDS bf16 tile
//   finalize: per b: M,L over 64 chunks; attn = e^(s-M)/L; ctx = sum wgt_c*part_c / L

typedef __attribute__((ext_vector_type(4))) float f32x4;
typedef __attribute__((ext_vector_type(8))) short short8;

#define B_  32
#define S_  4096
#define H_  512
#define A_  256

// ---- workspace layout (bytes) ----
#define WS_WT     0            // bf16 W_enc^T [256][512]   : 262144
#define WS_BIAS   262144       // fp32 [32][256]            : 32768
#define WS_SCORES 294912       // fp32 [32][4096]           : 524288
#define WS_M      819200       // fp32 [32][64]             : 8192
#define WS_L      827392       // fp32 [32][64]             : 8192
#define WS_PART   835584       // fp32 [32*64][512]         : 4194304

static __device__ __forceinline__ short f2bf(float f) {
  union { float f; uint32_t u; } v; v.f = f;
  uint32_t r = (v.u + 0x7FFFu + ((v.u >> 16) & 1u)) >> 16;
  return (short)(uint16_t)r;
}
static __device__ __forceinline__ float bf2f(uint32_t lo16) {
  union { uint32_t u; float f; } v; v.u = lo16 << 16; return v.f;
}

// ---------------- kernel 0: prep ------------------------------------------------
// blocks 0..31  : bias[b][col] = b_enc+b_dec + sum_k dh[b][k]*W_dec[k][col]
// blocks 32..63 : WT[n][k] = bf16(W_enc[k][n]) via LDS 64x64 tile transpose
__global__ __launch_bounds__(256) void prep_kernel(
    const float* __restrict__ dh, const float* __restrict__ W_enc,
    const float* __restrict__ b_enc, const float* __restrict__ W_dec,
    const float* __restrict__ b_dec, unsigned short* __restrict__ WT,
    float* __restrict__ bias) {
  __shared__ float dh_s[512];
  __shared__ unsigned short tile[64 * 66];
  const int tid = threadIdx.x;
  if (blockIdx.x < 32) {
    const int b = blockIdx.x;
    dh_s[tid]       = dh[(size_t)b * H_ + tid];
    dh_s[tid + 256] = dh[(size_t)b * H_ + tid + 256];
    __syncthreads();
    float s[4] = {0.f, 0.f, 0.f, 0.f};
    for (int k = 0; k < H_; k += 32) {
      #pragma unroll
      for (int j = 0; j < 32; ++j)
        s[j & 3] = fmaf(dh_s[k + j], W_dec[(size_t)(k + j) * A_ + tid], s[j & 3]);
    }
    bias[b * A_ + tid] = s[0] + s[1] + s[2] + s[3] + b_enc[tid] + b_dec[tid];
  } else {
    const int t = blockIdx.x - 32;          // 0..31
    const int kt = t >> 2, nt2 = t & 3;     // k-tile (8), n-tile (4)
    #pragma unroll
    for (int i = 0; i < 16; ++i) {
      int idx = tid + i * 256;              // 0..4095
      int kk = idx >> 6, nn = idx & 63;
      tile[kk * 66 + nn] =
          (unsigned short)f2bf(W_enc[(size_t)(kt * 64 + kk) * A_ + nt2 * 64 + nn]);
    }
    __syncthreads();
    #pragma unroll
    for (int i = 0; i < 16; ++i) {
      int idx = tid + i * 256;
      int nn = idx >> 6, kk = idx & 63;
      WT[(size_t)(nt2 * 64 + nn) * H_ + kt * 64 + kk] = tile[kk * 66 + nn];
    }
  }
}

// ---------------- kernel 1: fused scores + chunk-softmax + context partial ------
// grid 2048 = 32 b x 64 chunks of 64 rows; 4 waves, wave w owns rows w*16..+15.
__global__ __launch_bounds__(256, 2) void fused_kernel(
    const float* __restrict__ enc, const unsigned short* __restrict__ WT,
    const float* __restrict__ bias, const float* __restrict__ We,
    float* __restrict__ scores, float* __restrict__ wsm,
    float* __restrict__ wsl, float* __restrict__ part) {
  __shared__ __align__(16) unsigned short A_lds[64 * 520];  // 65 KiB, pad breaks conflicts
  __shared__ float s_sc[64];
  __shared__ float s_e[64];
  __shared__ float s_ml[2];

  const int tid = threadIdx.x, w = tid >> 6, lane = tid & 63;
  const int lm = lane & 15, lq = lane >> 4;
  const int b = blockIdx.x >> 6;
  const int chunk = blockIdx.x & 63;
  const int srow0 = blockIdx.x * 64;        // flat (b*S + s) row base
  const int arow_l = w * 16 + lm;           // local row 0..63

  f32x4 acc[16];
  #pragma unroll
  for (int nt = 0; nt < 16; ++nt) acc[nt] = (f32x4){0.f, 0.f, 0.f, 0.f};

  const float* ap = enc + (size_t)(srow0 + arow_l) * H_ + lq * 8;
  const unsigned short* wtp = WT + (size_t)lm * H_ + lq * 8;

  // ---- phase 1: GEMM, no barriers in k-loop ----
  float4 ca0 = *(const float4*)ap;
  float4 ca1 = *(const float4*)(ap + 4);
  for (int k0 = 0; k0 < H_; k0 += 32) {
    float4 na0, na1;
    const int kn = k0 + 32;
    if (kn < H_) { na0 = *(const float4*)(ap + kn); na1 = *(const float4*)(ap + kn + 4); }
    short8 af;
    af[0] = f2bf(ca0.x); af[1] = f2bf(ca0.y); af[2] = f2bf(ca0.z); af[3] = f2bf(ca0.w);
    af[4] = f2bf(ca1.x); af[5] = f2bf(ca1.y); af[6] = f2bf(ca1.z); af[7] = f2bf(ca1.w);
    *(short8*)&A_lds[arow_l * 520 + k0 + lq * 8] = af;   // bf16 stash for phase 2
    #pragma unroll
    for (int nt = 0; nt < 16; ++nt) {
      short8 bf = *(const short8*)(wtp + (size_t)nt * 16 * H_ + k0);  // L1/L2-hot
      acc[nt] = __builtin_amdgcn_mfma_f32_16x16x32_bf16(af, bf, acc[nt], 0, 0, 0);
    }
    if (kn < H_) { ca0 = na0; ca1 = na1; }
  }

  // ---- epilogue: score[row] = sum_col tanh(acc + bias)*We ----
  // C/D layout: col = lane&15, row = (lane>>4)*4 + reg
  float psum[4] = {0.f, 0.f, 0.f, 0.f};
  #pragma unroll
  for (int nt = 0; nt < 16; ++nt) {
    const int col = nt * 16 + lm;
    const float dp = bias[b * A_ + col];
    const float wv = We[col];
    #pragma unroll
    for (int r = 0; r < 4; ++r) {
      float x = acc[nt][r] + dp;
      float e = __expf(2.0f * x);
      float t = 1.0f - 2.0f * __builtin_amdgcn_rcpf(e + 1.0f);
      psum[r] = fmaf(t, wv, psum[r]);
    }
  }
  #pragma unroll
  for (int o = 1; o < 16; o <<= 1)
    #pragma unroll
    for (int r = 0; r < 4; ++r)
      psum[r] += __shfl_xor(psum[r], o, 64);
  if (lm == 0) {
    #pragma unroll
    for (int r = 0; r < 4; ++r) {
      const int rl = w * 16 + lq * 4 + r;
      s_sc[rl] = psum[r];
      scores[srow0 + rl] = psum[r];
    }
  }
  __syncthreads();

  // ---- chunk-local softmax state (wave 0) ----
  if (tid < 64) {
    float sc = s_sc[tid];
    float m = sc;
    #pragma unroll
    for (int o = 1; o < 64; o <<= 1) m = fmaxf(m, __shfl_xor(m, o, 64));
    float e = __expf(sc - m);
    float l = e;
    #pragma unroll
    for (int o = 1; o < 64; o <<= 1) l += __shfl_xor(l, o, 64);
    s_e[tid] = e;
    if (tid == 0) {
      wsm[b * 64 + chunk] = m;
      wsl[b * 64 + chunk] = l;
    }
  }
  __syncthreads();

  // ---- phase 2: context partial from LDS bf16 tile ----
  // thread t handles h = 2t, 2t+1
  float cx0 = 0.f, cx1 = 0.f;
  #pragma unroll 8
  for (int row = 0; row < 64; ++row) {
    uint32_t pv = *(const uint32_t*)&A_lds[row * 520 + (tid << 1)];
    float wr = s_e[row];                      // broadcast, conflict-free
    cx0 = fmaf(wr, bf2f(pv & 0xffffu), cx0);
    cx1 = fmaf(wr, bf2f(pv >> 16), cx1);
  }
  float2 o2; o2.x = cx0; o2.y = cx1;
  *(float2*)&part[(size_t)(b * 64 + chunk) * H_ + (tid << 1)] = o2;
}

// ---------------- kernel 2: finalize (per b: M,L; attn; ctx) --------------------
__global__ __launch_bounds__(256) void finalize_kernel(
    const float* __restrict__ scores, const float* __restrict__ wsm,
    const float* __restrict__ wsl, const float* __restrict__ part,
    float* __restrict__ ctx, float* __restrict__ attn) {
  __shared__ float wgt[64];
  __shared__ float s_ml[2];
  const int b = blockIdx.x, tid = threadIdx.x;
  if (tid < 64) {
    float mc = wsm[b * 64 + tid];
    float lc = wsl[b * 64 + tid];
    float M = mc;
    #pragma unroll
    for (int o = 1; o < 64; o <<= 1) M = fmaxf(M, __shfl_xor(M, o, 64));
    float wv = __expf(mc - M);
    float Lp = wv * lc;
    #pragma unroll
    for (int o = 1; o < 64; o <<= 1) Lp += __shfl_xor(Lp, o, 64);
    wgt[tid] = wv;
    if (tid == 0) { s_ml[0] = M; s_ml[1] = Lp; }
  }
  __syncthreads();
  const float M = s_ml[0];
  const float invL = 1.0f / s_ml[1];

  // context: h = tid, tid+256
  #pragma unroll
  for (int hh = 0; hh < 2; ++hh) {
    const int h = tid + hh * 256;
    float s = 0.f;
    #pragma unroll 8
    for (int c = 0; c < 64; ++c)
      s = fmaf(wgt[c], part[(size_t)(b * 64 + c) * H_ + h], s);
    ctx[(size_t)b * H_ + h] = s * invL;
  }
  // attn: 16 positions per thread
  #pragma unroll
  for (int i = 0; i < 16; ++i) {
    const int s_ = tid + i * 256;
    attn[(size_t)b * S_ + s_] = __expf(scores[(size_t)b * S_ + s_] - M) * invL;
  }
}

extern "C" void kernel_launch(void* const* d_in, const int* in_sizes, int n_in,
                              void* d_out, int out_size, void* d_ws, size_t ws_size,
                              hipStream_t stream) {
  const float* enc   = (const float*)d_in[0];
  const float* dh    = (const float*)d_in[1];
  const float* W_enc = (const float*)d_in[2];
  const float* b_enc = (const float*)d_in[3];
  const float* W_dec = (const float*)d_in[4];
  const float* b_dec = (const float*)d_in[5];
  const float* W_e   = (const float*)d_in[6];
  // b_e (d_in[7]) dropped: softmax is shift-invariant, scores not an output.

  char* ws = (char*)d_ws;
  unsigned short* WT = (unsigned short*)(ws + WS_WT);
  float* bias   = (float*)(ws + WS_BIAS);
  float* scores = (float*)(ws + WS_SCORES);
  float* wsm    = (float*)(ws + WS_M);
  float* wsl    = (float*)(ws + WS_L);
  float* part   = (float*)(ws + WS_PART);

  float* ctx  = (float*)d_out;            // [32][512]
  float* attn = (float*)d_out + B_ * H_;  // [32][4096]

  prep_kernel<<<dim3(64), dim3(256), 0, stream>>>(dh, W_enc, b_enc, W_dec, b_dec, WT, bias);
  fused_kernel<<<dim3(2048), dim3(256), 0, stream>>>(enc, WT, bias, W_e, scores, wsm, wsl, part);
  finalize_kernel<<<dim3(32), dim3(256), 0, stream>>>(scores, wsm, wsl, part, ctx, attn);
}

// Round 3
// 426.285 us; speedup vs baseline: 1.3777x; 1.3777x over previous
//
#include <hip/hip_runtime.h>
#include <hip/hip_bf16.h>
#include <stdint.h>

// AdditiveAttention: B=32, S=4096, H=512, A=256
// d_out = [context: 32*512][attn: 32*4096]  (fp32)
//
// R3: single pass over enc; B staged via global_load_lds into fragment-ordered
// LDS (double-buffered, 1 barrier/k-step); A global->VGPR prefetch; phase 2
// re-reads the block's rows from global (L2-hot). 128 rows/block.

typedef __attribute__((ext_vector_type(4))) float f32x4;
typedef __attribute__((ext_vector_type(8))) short short8;

#define B_  32
#define S_  4096
#define H_  512
#define A_  256
#define CHUNKS_ 32   // 4096 / 128 chunks per batch

// ---- workspace layout (bytes) ----
#define WS_WT     0            // bf16 W_enc^T [256][512]   : 262144
#define WS_BIAS   262144       // fp32 [32][256]            : 32768
#define WS_SCORES 294912       // fp32 [32][4096]           : 524288
#define WS_M      819200       // fp32 [32][32]             : 4096
#define WS_L      823296       // fp32 [32][32]             : 4096
#define WS_PART   827392       // fp32 [32*32][512]         : 2097152

static __device__ __forceinline__ short f2bf(float f) {
  union { float f; uint32_t u; } v; v.f = f;
  uint32_t r = (v.u + 0x7FFFu + ((v.u >> 16) & 1u)) >> 16;
  return (short)(uint16_t)r;
}

static __device__ __forceinline__ void gload_lds16(const void* g, void* l) {
  // async global->LDS: lane's 16B lands at (wave-uniform) l + lane*16
  __builtin_amdgcn_global_load_lds((const __attribute__((address_space(1))) void*)g,
                                   (__attribute__((address_space(3))) void*)l,
                                   16, 0, 0);
}

// ---------------- kernel 0: prep ------------------------------------------------
__global__ __launch_bounds__(256) void prep_kernel(
    const float* __restrict__ dh, const float* __restrict__ W_enc,
    const float* __restrict__ b_enc, const float* __restrict__ W_dec,
    const float* __restrict__ b_dec, unsigned short* __restrict__ WT,
    float* __restrict__ bias) {
  __shared__ float dh_s[512];
  __shared__ unsigned short tile[64 * 66];
  const int tid = threadIdx.x;
  if (blockIdx.x < 32) {
    const int b = blockIdx.x;
    dh_s[tid]       = dh[(size_t)b * H_ + tid];
    dh_s[tid + 256] = dh[(size_t)b * H_ + tid + 256];
    __syncthreads();
    float s[4] = {0.f, 0.f, 0.f, 0.f};
    for (int k = 0; k < H_; k += 32) {
      #pragma unroll
      for (int j = 0; j < 32; ++j)
        s[j & 3] = fmaf(dh_s[k + j], W_dec[(size_t)(k + j) * A_ + tid], s[j & 3]);
    }
    bias[b * A_ + tid] = s[0] + s[1] + s[2] + s[3] + b_enc[tid] + b_dec[tid];
  } else {
    const int t = blockIdx.x - 32;          // 0..31
    const int kt = t >> 2, nt2 = t & 3;     // k-tile (8), n-tile (4)
    #pragma unroll
    for (int i = 0; i < 16; ++i) {
      int idx = tid + i * 256;
      int kk = idx >> 6, nn = idx & 63;
      tile[kk * 66 + nn] =
          (unsigned short)f2bf(W_enc[(size_t)(kt * 64 + kk) * A_ + nt2 * 64 + nn]);
    }
    __syncthreads();
    #pragma unroll
    for (int i = 0; i < 16; ++i) {
      int idx = tid + i * 256;
      int nn = idx >> 6, kk = idx & 63;
      WT[(size_t)(nt2 * 64 + nn) * H_ + kt * 64 + kk] = tile[kk * 66 + nn];
    }
  }
}

// ---------------- kernel 1: fused scores + chunk-softmax + context partial ------
// grid 1024 = 32 b x 32 chunks of 128 rows. 4 waves; wave w rows w*32..w*32+31
// (2 m-tiles of 16). B [256 n][32 k] staged per k-step in fragment-lane order.
__global__ __launch_bounds__(256, 2) void fused_kernel(
    const float* __restrict__ enc, const unsigned short* __restrict__ WT,
    const float* __restrict__ bias, const float* __restrict__ We,
    float* __restrict__ scores, float* __restrict__ wsm,
    float* __restrict__ wsl, float* __restrict__ part) {
  __shared__ __align__(16) unsigned short Bb[2][8192];  // 2 x 16 KiB
  __shared__ float s_sc[128];
  __shared__ float s_e[128];
  __shared__ float s_red[4];

  const int tid = threadIdx.x, w = tid >> 6, lane = tid & 63;
  const int lm = lane & 15, lq = lane >> 4;
  const int b = blockIdx.x >> 5;
  const int chunk = blockIdx.x & 31;
  const int srow0 = blockIdx.x * 128;       // flat (b*S + s) row base

  f32x4 acc[2][16];
  #pragma unroll
  for (int mt = 0; mt < 2; ++mt)
    #pragma unroll
    for (int nt = 0; nt < 16; ++nt)
      acc[mt][nt] = (f32x4){0.f, 0.f, 0.f, 0.f};

  // A sources: row = srow0 + w*32 + mt*16 + lm, k-slice lq*8..+8
  const float* ap0 = enc + (size_t)(srow0 + w * 32 + lm) * H_ + lq * 8;
  const float* ap1 = ap0 + (size_t)16 * H_;

  // B staging source for wave w, chunk c (nt = w*4+c):
  //   lane reads WT[(nt*16 + lm)*H + k0 + lq*8 .. +8] -> LDS nt*1024 + lane*16
  const size_t bsrc_lane = (size_t)lm * H_ + lq * 8;

  // prologue: stage k0=0 into buf0, load A k0=0
  #pragma unroll
  for (int c = 0; c < 4; ++c) {
    const int nt = w * 4 + c;
    gload_lds16(WT + (size_t)nt * 16 * H_ + bsrc_lane,
                (char*)Bb + (size_t)nt * 1024);
  }
  float4 ca00 = *(const float4*)ap0, ca01 = *(const float4*)(ap0 + 4);
  float4 ca10 = *(const float4*)ap1, ca11 = *(const float4*)(ap1 + 4);

  for (int k0 = 0; k0 < H_; k0 += 32) {
    const int cur = (k0 >> 5) & 1;
    const int kn = k0 + 32;
    __syncthreads();   // buf[cur] staged (vmcnt drained), prev reads of buf[cur^1] done
    if (kn < H_) {
      #pragma unroll
      for (int c = 0; c < 4; ++c) {
        const int nt = w * 4 + c;
        gload_lds16(WT + (size_t)nt * 16 * H_ + kn + bsrc_lane,
                    (char*)Bb + (size_t)(cur ^ 1) * 16384 + (size_t)nt * 1024);
      }
    }
    float4 na00, na01, na10, na11;
    if (kn < H_) {
      na00 = *(const float4*)(ap0 + kn); na01 = *(const float4*)(ap0 + kn + 4);
      na10 = *(const float4*)(ap1 + kn); na11 = *(const float4*)(ap1 + kn + 4);
    }
    short8 af0, af1;
    af0[0] = f2bf(ca00.x); af0[1] = f2bf(ca00.y); af0[2] = f2bf(ca00.z); af0[3] = f2bf(ca00.w);
    af0[4] = f2bf(ca01.x); af0[5] = f2bf(ca01.y); af0[6] = f2bf(ca01.z); af0[7] = f2bf(ca01.w);
    af1[0] = f2bf(ca10.x); af1[1] = f2bf(ca10.y); af1[2] = f2bf(ca10.z); af1[3] = f2bf(ca10.w);
    af1[4] = f2bf(ca11.x); af1[5] = f2bf(ca11.y); af1[6] = f2bf(ca11.z); af1[7] = f2bf(ca11.w);
    const char* bbase = (const char*)Bb + (size_t)cur * 16384 + (size_t)lane * 16;
    #pragma unroll
    for (int nt = 0; nt < 16; ++nt) {
      short8 bf = *(const short8*)(bbase + (size_t)nt * 1024);  // ds_read_b128, conflict-free
      acc[0][nt] = __builtin_amdgcn_mfma_f32_16x16x32_bf16(af0, bf, acc[0][nt], 0, 0, 0);
      acc[1][nt] = __builtin_amdgcn_mfma_f32_16x16x32_bf16(af1, bf, acc[1][nt], 0, 0, 0);
    }
    if (kn < H_) { ca00 = na00; ca01 = na01; ca10 = na10; ca11 = na11; }
  }

  // ---- epilogue: score[row] = sum_col tanh(acc + bias)*We ----
  // C/D: col = lane&15, row(in 16-tile) = lq*4 + r  [m89/m91; R2-verified]
  float psum[2][4] = {{0, 0, 0, 0}, {0, 0, 0, 0}};
  #pragma unroll
  for (int nt = 0; nt < 16; ++nt) {
    const int col = nt * 16 + lm;
    const float dp = bias[b * A_ + col];
    const float wv = We[col];
    #pragma unroll
    for (int mt = 0; mt < 2; ++mt)
      #pragma unroll
      for (int r = 0; r < 4; ++r) {
        float x = acc[mt][nt][r] + dp;
        float e = __expf(2.0f * x);
        float t = 1.0f - 2.0f * __builtin_amdgcn_rcpf(e + 1.0f);
        psum[mt][r] = fmaf(t, wv, psum[mt][r]);
      }
  }
  #pragma unroll
  for (int o = 1; o < 16; o <<= 1)
    #pragma unroll
    for (int mt = 0; mt < 2; ++mt)
      #pragma unroll
      for (int r = 0; r < 4; ++r)
        psum[mt][r] += __shfl_xor(psum[mt][r], o, 64);
  if (lm == 0) {
    #pragma unroll
    for (int mt = 0; mt < 2; ++mt)
      #pragma unroll
      for (int r = 0; r < 4; ++r) {
        const int rl = w * 32 + mt * 16 + lq * 4 + r;
        s_sc[rl] = psum[mt][r];
        scores[srow0 + rl] = psum[mt][r];
      }
  }
  __syncthreads();

  // ---- chunk-local softmax over 128 rows (waves 0-1) ----
  float sc = 0.f;
  if (tid < 128) {
    sc = s_sc[tid];
    float m = sc;
    #pragma unroll
    for (int o = 1; o < 64; o <<= 1) m = fmaxf(m, __shfl_xor(m, o, 64));
    if (lane == 0) s_red[w] = m;
  }
  __syncthreads();
  if (tid < 128) {
    const float m = fmaxf(s_red[0], s_red[1]);
    const float e = __expf(sc - m);
    s_e[tid] = e;
    float l = e;
    #pragma unroll
    for (int o = 1; o < 64; o <<= 1) l += __shfl_xor(l, o, 64);
    if (lane == 0) s_red[2 + w] = l;
  }
  __syncthreads();
  if (tid == 0) {
    wsm[b * CHUNKS_ + chunk] = fmaxf(s_red[0], s_red[1]);
    wsl[b * CHUNKS_ + chunk] = s_red[2] + s_red[3];
  }

  // ---- phase 2: context partial; enc rows are L2-hot from phase 1 ----
  float cx0 = 0.f, cx1 = 0.f;
  const float* ebase = enc + (size_t)srow0 * H_ + (tid << 1);
  #pragma unroll 8
  for (int row = 0; row < 128; ++row) {
    float2 e = *(const float2*)(ebase + (size_t)row * H_);
    float wr = s_e[row];
    cx0 = fmaf(wr, e.x, cx0);
    cx1 = fmaf(wr, e.y, cx1);
  }
  float2 o2; o2.x = cx0; o2.y = cx1;
  *(float2*)&part[(size_t)(b * CHUNKS_ + chunk) * H_ + (tid << 1)] = o2;
}

// ---------------- kernel 2: finalize --------------------------------------------
__global__ __launch_bounds__(256) void finalize_kernel(
    const float* __restrict__ scores, const float* __restrict__ wsm,
    const float* __restrict__ wsl, const float* __restrict__ part,
    float* __restrict__ ctx, float* __restrict__ attn) {
  __shared__ float wgt[CHUNKS_];
  __shared__ float s_ml[2];
  const int b = blockIdx.x, tid = threadIdx.x;
  if (tid < 64) {
    float mc = (tid < CHUNKS_) ? wsm[b * CHUNKS_ + tid] : -1e30f;
    float lc = (tid < CHUNKS_) ? wsl[b * CHUNKS_ + tid] : 0.f;
    float M = mc;
    #pragma unroll
    for (int o = 1; o < 64; o <<= 1) M = fmaxf(M, __shfl_xor(M, o, 64));
    float wv = __expf(mc - M);
    float Lp = wv * lc;
    #pragma unroll
    for (int o = 1; o < 64; o <<= 1) Lp += __shfl_xor(Lp, o, 64);
    if (tid < CHUNKS_) wgt[tid] = wv;
    if (tid == 0) { s_ml[0] = M; s_ml[1] = Lp; }
  }
  __syncthreads();
  const float M = s_ml[0];
  const float invL = 1.0f / s_ml[1];

  #pragma unroll
  for (int hh = 0; hh < 2; ++hh) {
    const int h = tid + hh * 256;
    float s = 0.f;
    #pragma unroll 8
    for (int c = 0; c < CHUNKS_; ++c)
      s = fmaf(wgt[c], part[(size_t)(b * CHUNKS_ + c) * H_ + h], s);
    ctx[(size_t)b * H_ + h] = s * invL;
  }
  #pragma unroll
  for (int i = 0; i < 16; ++i) {
    const int s_ = tid + i * 256;
    attn[(size_t)b * S_ + s_] = __expf(scores[(size_t)b * S_ + s_] - M) * invL;
  }
}

extern "C" void kernel_launch(void* const* d_in, const int* in_sizes, int n_in,
                              void* d_out, int out_size, void* d_ws, size_t ws_size,
                              hipStream_t stream) {
  const float* enc   = (const float*)d_in[0];
  const float* dh    = (const float*)d_in[1];
  const float* W_enc = (const float*)d_in[2];
  const float* b_enc = (const float*)d_in[3];
  const float* W_dec = (const float*)d_in[4];
  const float* b_dec = (const float*)d_in[5];
  const float* W_e   = (const float*)d_in[6];
  // b_e (d_in[7]) dropped: softmax is shift-invariant, scores not an output.

  char* ws = (char*)d_ws;
  unsigned short* WT = (unsigned short*)(ws + WS_WT);
  float* bias   = (float*)(ws + WS_BIAS);
  float* scores = (float*)(ws + WS_SCORES);
  float* wsm    = (float*)(ws + WS_M);
  float* wsl    = (float*)(ws + WS_L);
  float* part   = (float*)(ws + WS_PART);

  float* ctx  = (float*)d_out;            // [32][512]
  float* attn = (float*)d_out + B_ * H_;  // [32][4096]

  prep_kernel<<<dim3(64), dim3(256), 0, stream>>>(dh, W_enc, b_enc, W_dec, b_dec, WT, bias);
  fused_kernel<<<dim3(1024), dim3(256), 0, stream>>>(enc, WT, bias, W_e, scores, wsm, wsl, part);
  finalize_kernel<<<dim3(32), dim3(256), 0, stream>>>(scores, wsm, wsl, part, ctx, attn);
}

// Round 4
// 419.345 us; speedup vs baseline: 1.4006x; 1.0165x over previous
//
#include <hip/hip_runtime.h>
#include <hip/hip_bf16.h>
#include <stdint.h>

// AdditiveAttention: B=32, S=4096, H=512, A=256
// d_out = [context: 32*512][attn: 32*4096]  (fp32)
//
// R4: ONE pass over enc. 64-row blocks (2048 blocks, 2/CU). A: global fp32 ->
// VGPR -> bf16 -> LDS stash [64][520] (phase-2 context reads LDS, not global).
// B: per-wave VGPR register ring (lead-2) straight from L2-hot WT — no B LDS,
// no staging barrier. ONE barrier per k-step (stash k-regions disjoint).

typedef __attribute__((ext_vector_type(4))) float f32x4;
typedef __attribute__((ext_vector_type(8))) short short8;

#define B_  32
#define S_  4096
#define H_  512
#define A_  256
#define CHUNKS_ 64   // 4096 / 64 rows per block

// ---- workspace layout (bytes) ----
#define WS_WT     0            // bf16 W_enc^T [256][512]   : 262144
#define WS_BIAS   262144       // fp32 [32][256]            : 32768
#define WS_SCORES 294912       // fp32 [32][4096]           : 524288
#define WS_M      819200       // fp32 [32][64]             : 8192
#define WS_L      827392       // fp32 [32][64]             : 8192
#define WS_PART   835584       // fp32 [32*64][512]         : 4194304

#define STRIDE_ 520            // stash row stride in shorts (1040 B, 16B-aligned, depadded banks)

static __device__ __forceinline__ short f2bf(float f) {
  union { float f; uint32_t u; } v; v.f = f;
  uint32_t r = (v.u + 0x7FFFu + ((v.u >> 16) & 1u)) >> 16;
  return (short)(uint16_t)r;
}
static __device__ __forceinline__ float bf2f(uint32_t lo16) {
  union { uint32_t u; float f; } v; v.u = lo16 << 16; return v.f;
}

// ---------------- kernel 0: prep ------------------------------------------------
__global__ __launch_bounds__(256) void prep_kernel(
    const float* __restrict__ dh, const float* __restrict__ W_enc,
    const float* __restrict__ b_enc, const float* __restrict__ W_dec,
    const float* __restrict__ b_dec, unsigned short* __restrict__ WT,
    float* __restrict__ bias) {
  __shared__ float dh_s[512];
  __shared__ unsigned short tile[64 * 66];
  const int tid = threadIdx.x;
  if (blockIdx.x < 32) {
    const int b = blockIdx.x;
    dh_s[tid]       = dh[(size_t)b * H_ + tid];
    dh_s[tid + 256] = dh[(size_t)b * H_ + tid + 256];
    __syncthreads();
    float s[4] = {0.f, 0.f, 0.f, 0.f};
    for (int k = 0; k < H_; k += 32) {
      #pragma unroll
      for (int j = 0; j < 32; ++j)
        s[j & 3] = fmaf(dh_s[k + j], W_dec[(size_t)(k + j) * A_ + tid], s[j & 3]);
    }
    bias[b * A_ + tid] = s[0] + s[1] + s[2] + s[3] + b_enc[tid] + b_dec[tid];
  } else {
    const int t = blockIdx.x - 32;          // 0..31
    const int kt = t >> 2, nt2 = t & 3;     // k-tile (8), n-tile (4)
    #pragma unroll
    for (int i = 0; i < 16; ++i) {
      int idx = tid + i * 256;
      int kk = idx >> 6, nn = idx & 63;
      tile[kk * 66 + nn] =
          (unsigned short)f2bf(W_enc[(size_t)(kt * 64 + kk) * A_ + nt2 * 64 + nn]);
    }
    __syncthreads();
    #pragma unroll
    for (int i = 0; i < 16; ++i) {
      int idx = tid + i * 256;
      int nn = idx >> 6, kk = idx & 63;
      WT[(size_t)(nt2 * 64 + nn) * H_ + kt * 64 + kk] = tile[kk * 66 + nn];
    }
  }
}

// ---------------- kernel 1: fused -----------------------------------------------
// grid 2048 = 32 b x 64 chunks of 64 rows. 4 waves; wave w owns col-tiles
// nt_g = w*4..w*4+3 (cols w*64..+63), all 4 m-tiles (rows 0..63).
__global__ __launch_bounds__(256, 2) void fused_kernel(
    const float* __restrict__ enc, const unsigned short* __restrict__ WT,
    const float* __restrict__ bias, const float* __restrict__ We,
    float* __restrict__ scores, float* __restrict__ wsm,
    float* __restrict__ wsl, float* __restrict__ part) {
  __shared__ __align__(16) unsigned short stash[64 * STRIDE_];  // 66560 B
  __shared__ float s_ps[4][64];                                  // per-wave row partials
  __shared__ float s_e[64];

  const int tid = threadIdx.x, w = tid >> 6, lane = tid & 63;
  const int lm = lane & 15, lq = lane >> 4;
  const int b = blockIdx.x >> 6;
  const int chunk = blockIdx.x & 63;
  const int srow0 = blockIdx.x * 64;        // flat (b*S + s) row base

  f32x4 acc[4][4];
  #pragma unroll
  for (int mt = 0; mt < 4; ++mt)
    #pragma unroll
    for (int nt = 0; nt < 4; ++nt)
      acc[mt][nt] = (f32x4){0.f, 0.f, 0.f, 0.f};

  // ---- A staging addressing: thread t loads row tid>>2, k-span (tid&3)*8..+8
  const int arow = tid >> 2, akoff = (tid & 3) * 8;
  const float* aptr = enc + (size_t)(srow0 + arow) * H_ + akoff;
  unsigned short* swp = &stash[arow * STRIDE_ + akoff];

  // ---- B reg-ring addressing: lane's frag for nt_g = w*4+j:
  //      WT[(nt_g*16+lm)*512 + kstep*32 + lq*8]
  const unsigned short* bptr = WT + (size_t)((w * 4) * 16 + lm) * H_ + lq * 8;

  short8 Bring[3][4];
  float4 abuf0_a, abuf0_b, abuf1_a, abuf1_b;

  // ---- prologue ----
  abuf0_a = *(const float4*)aptr;
  abuf0_b = *(const float4*)(aptr + 4);
  {
    short8 sv;
    sv[0] = f2bf(abuf0_a.x); sv[1] = f2bf(abuf0_a.y); sv[2] = f2bf(abuf0_a.z); sv[3] = f2bf(abuf0_a.w);
    sv[4] = f2bf(abuf0_b.x); sv[5] = f2bf(abuf0_b.y); sv[6] = f2bf(abuf0_b.z); sv[7] = f2bf(abuf0_b.w);
    *(short8*)swp = sv;                     // stash[k=0]
  }
  abuf1_a = *(const float4*)(aptr + 32);    // A(k=1)
  abuf1_b = *(const float4*)(aptr + 36);
  #pragma unroll
  for (int j = 0; j < 4; ++j) {
    Bring[0][j] = *(const short8*)(bptr + (size_t)j * 16 * H_);        // B(0)
    Bring[1][j] = *(const short8*)(bptr + (size_t)j * 16 * H_ + 32);   // B(1)
  }
  __syncthreads();                          // stash[0] visible

  #pragma unroll
  for (int k = 0; k < 16; ++k) {
    const int kel = k * 32;                 // k element base
    // prefetch A(k+2) into the buffer freed at step k-1
    float4 na_a, na_b;
    if (k + 2 < 16) {
      na_a = *(const float4*)(aptr + (k + 2) * 32);
      na_b = *(const float4*)(aptr + (k + 2) * 32 + 4);
    }
    // prefetch B(k+2) into ring slot (k+2)%3
    if (k + 2 < 16) {
      #pragma unroll
      for (int j = 0; j < 4; ++j)
        Bring[(k + 2) % 3][j] = *(const short8*)(bptr + (size_t)j * 16 * H_ + (k + 2) * 32);
    }
    // A fragments from stash; MFMA
    #pragma unroll
    for (int mt = 0; mt < 4; ++mt) {
      short8 af = *(const short8*)&stash[(mt * 16 + lm) * STRIDE_ + kel + lq * 8];
      #pragma unroll
      for (int j = 0; j < 4; ++j)
        acc[mt][j] = __builtin_amdgcn_mfma_f32_16x16x32_bf16(af, Bring[k % 3][j], acc[mt][j], 0, 0, 0);
    }
    // write stash[k+1] from the A(k+1) buffer (issued at step k-1 / prologue)
    if (k < 15) {
      float4 ca = (k & 1) ? abuf0_a : abuf1_a;
      float4 cb = (k & 1) ? abuf0_b : abuf1_b;
      short8 sv;
      sv[0] = f2bf(ca.x); sv[1] = f2bf(ca.y); sv[2] = f2bf(ca.z); sv[3] = f2bf(ca.w);
      sv[4] = f2bf(cb.x); sv[5] = f2bf(cb.y); sv[6] = f2bf(cb.z); sv[7] = f2bf(cb.w);
      *(short8*)(swp + (k + 1) * 32) = sv;
    }
    if (k + 2 < 16) {
      if (k & 1) { abuf1_a = na_a; abuf1_b = na_b; }
      else       { abuf0_a = na_a; abuf0_b = na_b; }
    }
    __syncthreads();                        // stash[k+1] visible; frag reads done
  }

  // ---- epilogue: per-wave partial score over its 64 cols ----
  // C/D: col = (w*4+j)*16 + lm, row(in mt) = lq*4 + r
  float psum[4][4] = {{0,0,0,0},{0,0,0,0},{0,0,0,0},{0,0,0,0}};
  #pragma unroll
  for (int j = 0; j < 4; ++j) {
    const int col = (w * 4 + j) * 16 + lm;
    const float dp = bias[b * A_ + col];
    const float wv = We[col];
    #pragma unroll
    for (int mt = 0; mt < 4; ++mt)
      #pragma unroll
      for (int r = 0; r < 4; ++r) {
        float x = acc[mt][j][r] + dp;
        float e = __expf(2.0f * x);
        float t = 1.0f - 2.0f * __builtin_amdgcn_rcpf(e + 1.0f);
        psum[mt][r] = fmaf(t, wv, psum[mt][r]);
      }
  }
  #pragma unroll
  for (int o = 1; o < 16; o <<= 1)
    #pragma unroll
    for (int mt = 0; mt < 4; ++mt)
      #pragma unroll
      for (int r = 0; r < 4; ++r)
        psum[mt][r] += __shfl_xor(psum[mt][r], o, 64);
  if (lm == 0) {
    #pragma unroll
    for (int mt = 0; mt < 4; ++mt)
      #pragma unroll
      for (int r = 0; r < 4; ++r)
        s_ps[w][mt * 16 + lq * 4 + r] = psum[mt][r];
  }
  __syncthreads();

  // ---- cross-wave sum, chunk softmax (wave 0) ----
  if (tid < 64) {
    const float sc = s_ps[0][tid] + s_ps[1][tid] + s_ps[2][tid] + s_ps[3][tid];
    scores[srow0 + tid] = sc;
    float m = sc;
    #pragma unroll
    for (int o = 1; o < 64; o <<= 1) m = fmaxf(m, __shfl_xor(m, o, 64));
    const float e = __expf(sc - m);
    float l = e;
    #pragma unroll
    for (int o = 1; o < 64; o <<= 1) l += __shfl_xor(l, o, 64);
    s_e[tid] = e;
    if (tid == 0) {
      wsm[b * CHUNKS_ + chunk] = m;
      wsl[b * CHUNKS_ + chunk] = l;
    }
  }
  __syncthreads();

  // ---- phase 2: context partial from LDS stash (no global enc re-read) ----
  float cx0 = 0.f, cx1 = 0.f;
  #pragma unroll 8
  for (int row = 0; row < 64; ++row) {
    uint32_t pv = *(const uint32_t*)&stash[row * STRIDE_ + (tid << 1)];
    float wr = s_e[row];
    cx0 = fmaf(wr, bf2f(pv & 0xffffu), cx0);
    cx1 = fmaf(wr, bf2f(pv >> 16), cx1);
  }
  float2 o2; o2.x = cx0; o2.y = cx1;
  *(float2*)&part[(size_t)(b * CHUNKS_ + chunk) * H_ + (tid << 1)] = o2;
}

// ---------------- kernel 2: finalize --------------------------------------------
__global__ __launch_bounds__(256) void finalize_kernel(
    const float* __restrict__ scores, const float* __restrict__ wsm,
    const float* __restrict__ wsl, const float* __restrict__ part,
    float* __restrict__ ctx, float* __restrict__ attn) {
  __shared__ float wgt[CHUNKS_];
  __shared__ float s_ml[2];
  const int b = blockIdx.x, tid = threadIdx.x;
  if (tid < 64) {
    float mc = wsm[b * CHUNKS_ + tid];
    float lc = wsl[b * CHUNKS_ + tid];
    float M = mc;
    #pragma unroll
    for (int o = 1; o < 64; o <<= 1) M = fmaxf(M, __shfl_xor(M, o, 64));
    float wv = __expf(mc - M);
    float Lp = wv * lc;
    #pragma unroll
    for (int o = 1; o < 64; o <<= 1) Lp += __shfl_xor(Lp, o, 64);
    wgt[tid] = wv;
    if (tid == 0) { s_ml[0] = M; s_ml[1] = Lp; }
  }
  __syncthreads();
  const float M = s_ml[0];
  const float invL = 1.0f / s_ml[1];

  #pragma unroll
  for (int hh = 0; hh < 2; ++hh) {
    const int h = tid + hh * 256;
    float s = 0.f;
    #pragma unroll 8
    for (int c = 0; c < CHUNKS_; ++c)
      s = fmaf(wgt[c], part[(size_t)(b * CHUNKS_ + c) * H_ + h], s);
    ctx[(size_t)b * H_ + h] = s * invL;
  }
  #pragma unroll
  for (int i = 0; i < 16; ++i) {
    const int s_ = tid + i * 256;
    attn[(size_t)b * S_ + s_] = __expf(scores[(size_t)b * S_ + s_] - M) * invL;
  }
}

extern "C" void kernel_launch(void* const* d_in, const int* in_sizes, int n_in,
                              void* d_out, int out_size, void* d_ws, size_t ws_size,
                              hipStream_t stream) {
  const float* enc   = (const float*)d_in[0];
  const float* dh    = (const float*)d_in[1];
  const float* W_enc = (const float*)d_in[2];
  const float* b_enc = (const float*)d_in[3];
  const float* W_dec = (const float*)d_in[4];
  const float* b_dec = (const float*)d_in[5];
  const float* W_e   = (const float*)d_in[6];
  // b_e (d_in[7]) dropped: softmax is shift-invariant, scores not an output.

  char* ws = (char*)d_ws;
  unsigned short* WT = (unsigned short*)(ws + WS_WT);
  float* bias   = (float*)(ws + WS_BIAS);
  float* scores = (float*)(ws + WS_SCORES);
  float* wsm    = (float*)(ws + WS_M);
  float* wsl    = (float*)(ws + WS_L);
  float* part   = (float*)(ws + WS_PART);

  float* ctx  = (float*)d_out;            // [32][512]
  float* attn = (float*)d_out + B_ * H_;  // [32][4096]

  prep_kernel<<<dim3(64), dim3(256), 0, stream>>>(dh, W_enc, b_enc, W_dec, b_dec, WT, bias);
  fused_kernel<<<dim3(2048), dim3(256), 0, stream>>>(enc, WT, bias, W_e, scores, wsm, wsl, part);
  finalize_kernel<<<dim3(32), dim3(256), 0, stream>>>(scores, wsm, wsl, part, ctx, attn);
}